// Round 4
// baseline (749.799 us; speedup 1.0000x reference)
//
#include <hip/hip_runtime.h>
#include <hip/hip_bf16.h>
#include <stdint.h>

typedef unsigned short u16;
typedef unsigned int u32;
typedef __attribute__((ext_vector_type(8))) __bf16 bf16x8;
typedef __attribute__((ext_vector_type(4))) float f32x4;

#define NEG_SLOPE 0.2f

__device__ __forceinline__ float bf2f(u16 u) {
    return __uint_as_float(((u32)u) << 16);
}
__device__ __forceinline__ u16 f2bf(float f) {
    u32 x = __float_as_uint(f);
    u32 r = (x + 0x7fffu + ((x >> 16) & 1u)) >> 16;  // round-to-nearest-even
    return (u16)r;
}

// ---------------- fused prep: cast x->bf16, transpose W1/W2, init deg ----------------

__global__ void prep_kernel(const float* __restrict__ x, const float* __restrict__ W1,
                            const float* __restrict__ W2, u16* __restrict__ xb,
                            u16* __restrict__ w1t, u16* __restrict__ w2t,
                            int* __restrict__ deg, int N) {
    int t = blockIdx.x * blockDim.x + threadIdx.x;
    int r1 = N * 32;            // x cast, float4 granules
    int r2 = r1 + 512 * 128;    // W1[128,512] -> w1t[512,128]
    int r3 = r2 + 64 * 512;     // W2[512,40] -> w2t[64,512] (pad rows 40..63)
    int r4 = r3 + N;            // deg init
    if (t < r1) {
        int base = t * 4;
        float4 v = *(const float4*)(x + base);
        xb[base + 0] = f2bf(v.x);
        xb[base + 1] = f2bf(v.y);
        xb[base + 2] = f2bf(v.z);
        xb[base + 3] = f2bf(v.w);
    } else if (t < r2) {
        int i = t - r1;
        int nn = i >> 7, k = i & 127;
        w1t[i] = f2bf(W1[k * 512 + nn]);
    } else if (t < r3) {
        int i = t - r2;
        int nn = i >> 9, k = i & 511;
        w2t[i] = (nn < 40) ? f2bf(W2[k * 40 + nn]) : (u16)0;
    } else if (t < r4) {
        deg[t - r3] = 1;  // self loop
    }
}

// ---------------- CSR build ----------------

__global__ void hist_kernel(const int* __restrict__ dst, int* deg, int E) {
    int e = blockIdx.x * blockDim.x + threadIdx.x;
    if (e < E) atomicAdd(&deg[dst[e]], 1);
}

__global__ void scan_kernel(const int* __restrict__ deg, int* offsets, int* cursor, int N) {
    __shared__ int s[1024];
    int t = threadIdx.x;
    int chunk = (N + 1023) / 1024;
    int beg = t * chunk;
    int end = beg + chunk; if (end > N) end = N; if (beg > N) beg = N;
    int sum = 0;
    for (int i = beg; i < end; i++) sum += deg[i];
    s[t] = sum;
    __syncthreads();
    for (int off = 1; off < 1024; off <<= 1) {
        int v = (t >= off) ? s[t - off] : 0;
        __syncthreads();
        s[t] += v;
        __syncthreads();
    }
    int run = s[t] - sum;  // exclusive prefix
    for (int i = beg; i < end; i++) {
        offsets[i] = run;
        cursor[i] = run;
        run += deg[i];
    }
    if (t == 1023) offsets[N] = s[1023];
}

__global__ void scatter_kernel(const int* __restrict__ src, const int* __restrict__ dst,
                               int* cursor, int* esrc, int E, int N) {
    int e = blockIdx.x * blockDim.x + threadIdx.x;
    if (e < E) {
        int d = dst[e];
        int idx = atomicAdd(&cursor[d], 1);
        esrc[idx] = src[e];
    } else if (e < E + N) {
        int i = e - E;
        int idx = atomicAdd(&cursor[i], 1);
        esrc[idx] = i;
    }
}

// ---------------- bf16 MFMA GEMM ----------------
// C[M, ldc] = A[M, K](bf16) @ Bt[Ncols, K](bf16)^T, store cols < Nstore.
// Block tile BM x BN, 4 waves in 2x2 of (BM/2)x(BN/2). LDS rows padded to
// 40 bf16 (80 B): 16-lane frag reads 2-way bank-aliased = free (m136).

template <int BM, int BN, bool CBF16>
__global__ __launch_bounds__(256) void mfma_gemm(
    const u16* __restrict__ A, const u16* __restrict__ Bt, void* __restrict__ Cv,
    int M, int K, int Nstore, int ldc) {
    constexpr int LDT = 40;
    constexpr int MI = BM / 32, NI = BN / 32;
    __shared__ u16 As[BM * LDT];
    __shared__ u16 Bs[BN * LDT];
    const int tid = threadIdx.x;
    const int r0 = blockIdx.x * BM;
    const int c0 = blockIdx.y * BN;
    const int lane = tid & 63, w = tid >> 6;
    const int quad = lane >> 4, l16 = lane & 15;
    const int wm = (w >> 1) * (BM / 2);
    const int wn = (w & 1) * (BN / 2);
    f32x4 acc[MI][NI] = {};

    for (int kc = 0; kc < K; kc += 32) {
        // ---- stage A: BM rows x 32 bf16 ----
        if constexpr (BM == 128) {
            int row = tid >> 1, half = tid & 1;
            int gr = r0 + row;
            uint4 v0 = make_uint4(0u, 0u, 0u, 0u), v1 = v0;
            if (gr < M) {
                const u16* p = A + (size_t)gr * K + kc + half * 16;
                v0 = *(const uint4*)p;
                v1 = *(const uint4*)(p + 8);
            }
            *(uint4*)&As[row * LDT + half * 16] = v0;
            *(uint4*)&As[row * LDT + half * 16 + 8] = v1;
        } else {  // BM == 64
            int row = tid >> 2, qo = (tid & 3) * 8;
            int gr = r0 + row;
            uint4 v = make_uint4(0u, 0u, 0u, 0u);
            if (gr < M) v = *(const uint4*)(A + (size_t)gr * K + kc + qo);
            *(uint4*)&As[row * LDT + qo] = v;
        }
        // ---- stage B: BN rows x 32 bf16 (Bt is padded, no guard) ----
        if constexpr (BN == 128) {
            int row = tid >> 1, half = tid & 1;
            const u16* p = Bt + (size_t)(c0 + row) * K + kc + half * 16;
            uint4 v0 = *(const uint4*)p;
            uint4 v1 = *(const uint4*)(p + 8);
            *(uint4*)&Bs[row * LDT + half * 16] = v0;
            *(uint4*)&Bs[row * LDT + half * 16 + 8] = v1;
        } else {  // BN == 64
            int row = tid >> 2, qo = (tid & 3) * 8;
            uint4 v = *(const uint4*)(Bt + (size_t)(c0 + row) * K + kc + qo);
            *(uint4*)&Bs[row * LDT + qo] = v;
        }
        __syncthreads();

        bf16x8 af[MI], bfr[NI];
#pragma unroll
        for (int mi = 0; mi < MI; mi++) {
            uint4 v = *(const uint4*)&As[(wm + mi * 16 + l16) * LDT + quad * 8];
            af[mi] = __builtin_bit_cast(bf16x8, v);
        }
#pragma unroll
        for (int ni = 0; ni < NI; ni++) {
            uint4 v = *(const uint4*)&Bs[(wn + ni * 16 + l16) * LDT + quad * 8];
            bfr[ni] = __builtin_bit_cast(bf16x8, v);
        }
#pragma unroll
        for (int mi = 0; mi < MI; mi++)
#pragma unroll
            for (int ni = 0; ni < NI; ni++)
                acc[mi][ni] = __builtin_amdgcn_mfma_f32_16x16x32_bf16(
                    af[mi], bfr[ni], acc[mi][ni], 0, 0, 0);
        __syncthreads();
    }
    // epilogue: D row = quad*4 + reg, col = l16 (verified m89/m91 mapping)
#pragma unroll
    for (int mi = 0; mi < MI; mi++) {
#pragma unroll
        for (int r = 0; r < 4; r++) {
            int gr = r0 + wm + mi * 16 + quad * 4 + r;
            if (gr >= M) continue;
#pragma unroll
            for (int ni = 0; ni < NI; ni++) {
                int gc = c0 + wn + ni * 16 + l16;
                if (gc >= Nstore) continue;
                if (CBF16)
                    ((u16*)Cv)[(size_t)gr * ldc + gc] = f2bf(acc[mi][ni][r]);
                else
                    ((float*)Cv)[(size_t)gr * ldc + gc] = acc[mi][ni][r];
            }
        }
    }
}

// ---------------- layer-1 attention ----------------

__global__ void logits1_kernel(const u16* __restrict__ h, const float* __restrict__ a_src,
                               const float* __restrict__ a_dst, float* als, float* ald, int N) {
    int t = blockIdx.x * blockDim.x + threadIdx.x;
    if (t >= N * 8) return;
    int n = t >> 3, hd = t & 7;
    const u16* row = h + (size_t)n * 512 + hd * 64;
    float s = 0.f, d = 0.f;
#pragma unroll
    for (int i = 0; i < 8; i++) {
        uint4 v = *(const uint4*)(row + i * 8);
        const u16* p = (const u16*)&v;
#pragma unroll
        for (int q = 0; q < 8; q++) {
            float x = bf2f(p[q]);
            s = fmaf(x, a_src[hd * 64 + i * 8 + q], s);
            d = fmaf(x, a_dst[hd * 64 + i * 8 + q], d);
        }
    }
    als[t] = s;
    ald[t] = d;
}

// Fused softmax + aggregation, layer 1. One BLOCK per destination node;
// 4 waves split the edge list (stride 4*64), each wave reads full 1KB h rows
// coalesced (16B/lane); partial (acc, z) combined through LDS.
__global__ __launch_bounds__(256) void agg1_fused(
    const int* __restrict__ offs, const int* __restrict__ esrc,
    const u16* __restrict__ h, const float* __restrict__ als,
    const float* __restrict__ ald, const float* __restrict__ b1,
    u16* __restrict__ h2, int N) {
    __shared__ float sacc[4][512];
    __shared__ float sz[4][8];
    int wid = blockIdx.x;
    int w = threadIdx.x >> 6;
    int lane = threadIdx.x & 63;
    int hd = lane >> 3;
    int b = offs[wid], e = offs[wid + 1];
    float ad = ald[wid * 8 + hd];
    float acc[8] = {};
    float zs = 0.f;
    const u16* hp = h + (size_t)lane * 8;
    for (int jb = b + w * 64; jb < e; jb += 256) {
        int nk = min(64, e - jb);
        int my = (jb + lane < e) ? esrc[jb + lane] : 0;
        for (int k = 0; k < nk; k++) {
            int s = __shfl(my, k);
            float v = als[s * 8 + hd] + ad;
            v = v > 0.f ? v : NEG_SLOPE * v;
            float wt = __expf(v);
            zs += wt;  // identical across the 8 lanes of a head
            uint4 hv = *(const uint4*)(hp + (size_t)s * 512);
            const u16* p = (const u16*)&hv;
#pragma unroll
            for (int q = 0; q < 8; q++) acc[q] = fmaf(wt, bf2f(p[q]), acc[q]);
        }
    }
    *(float4*)&sacc[w][lane * 8] = make_float4(acc[0], acc[1], acc[2], acc[3]);
    *(float4*)&sacc[w][lane * 8 + 4] = make_float4(acc[4], acc[5], acc[6], acc[7]);
    if ((lane & 7) == 0) sz[w][hd] = zs;
    __syncthreads();
    // 256 threads x 2 channels each
    int c = threadIdx.x * 2;
    float a0 = sacc[0][c] + sacc[1][c] + sacc[2][c] + sacc[3][c];
    float a1 = sacc[0][c + 1] + sacc[1][c + 1] + sacc[2][c + 1] + sacc[3][c + 1];
    int zh = c >> 6;
    float z = sz[0][zh] + sz[1][zh] + sz[2][zh] + sz[3][zh];
    float zi = 1.f / z;  // >0: self loop guarantees at least one edge
    float v0 = fmaf(a0, zi, b1[c]);
    float v1 = fmaf(a1, zi, b1[c + 1]);
    v0 = v0 > 0.f ? v0 : 0.f;  // inter-layer ReLU
    v1 = v1 > 0.f ? v1 : 0.f;
    u32 pack = (u32)f2bf(v0) | ((u32)f2bf(v1) << 16);
    *(u32*)&h2[(size_t)wid * 512 + c] = pack;
}

// ---------------- layer-2 attention ----------------

__global__ void logits2_kernel(const float* __restrict__ g, const float* __restrict__ a_src,
                               const float* __restrict__ a_dst, float* als, float* ald, int N) {
    int n = blockIdx.x * blockDim.x + threadIdx.x;
    if (n >= N) return;
    const float* row = g + (size_t)n * 40;
    float s = 0.f, d = 0.f;
#pragma unroll
    for (int i = 0; i < 10; i++) {
        float4 v = *(const float4*)(row + i * 4);
        float vv[4] = {v.x, v.y, v.z, v.w};
#pragma unroll
        for (int q = 0; q < 4; q++) {
            s = fmaf(vv[q], a_src[i * 4 + q], s);
            d = fmaf(vv[q], a_dst[i * 4 + q], d);
        }
    }
    als[n] = s;
    ald[n] = d;
}

// Fused softmax + aggregation, layer 2. Two nodes per block, 2 waves per
// node splitting the edge list; lane = class (<40); LDS combine.
__global__ __launch_bounds__(256) void agg2_fused(
    const int* __restrict__ offs, const int* __restrict__ esrc,
    const float* __restrict__ g, const float* __restrict__ als,
    const float* __restrict__ ald, const float* __restrict__ b2,
    float* __restrict__ out, int N) {
    __shared__ float sacc[4][64];
    __shared__ float sz[4];
    int w = threadIdx.x >> 6;
    int lane = threadIdx.x & 63;
    int node = blockIdx.x * 2 + (w >> 1);
    int wh = w & 1;
    float acc = 0.f, zs = 0.f;
    if (node < N) {
        int b = offs[node], e = offs[node + 1];
        float ad = ald[node];
        bool active = lane < 40;
        for (int jb = b + wh * 64; jb < e; jb += 128) {
            int nk = min(64, e - jb);
            int my = (jb + lane < e) ? esrc[jb + lane] : 0;
            for (int k = 0; k < nk; k++) {
                int s = __shfl(my, k);
                float v = als[s] + ad;
                v = v > 0.f ? v : NEG_SLOPE * v;
                float wt = __expf(v);
                zs += wt;
                if (active) acc = fmaf(wt, g[(size_t)s * 40 + lane], acc);
            }
        }
        sacc[w][lane] = acc;
        if (lane == 0) sz[w] = zs;
    }
    __syncthreads();
    if (node < N && wh == 0 && lane < 40) {
        float a = sacc[w][lane] + sacc[w + 1][lane];
        float z = sz[w] + sz[w + 1];
        out[(size_t)node * 40 + lane] = a / z + b2[lane];
    }
}

// ---------------- host launch ----------------

extern "C" void kernel_launch(void* const* d_in, const int* in_sizes, int n_in,
                              void* d_out, int out_size, void* d_ws, size_t ws_size,
                              hipStream_t stream) {
    const float* x   = (const float*)d_in[0];
    const int*   ei  = (const int*)d_in[1];
    const float* W1  = (const float*)d_in[2];
    const float* a1s = (const float*)d_in[3];
    const float* a1d = (const float*)d_in[4];
    const float* b1  = (const float*)d_in[5];
    const float* W2  = (const float*)d_in[6];
    const float* a2s = (const float*)d_in[7];
    const float* a2d = (const float*)d_in[8];
    const float* b2  = (const float*)d_in[9];
    float* out = (float*)d_out;

    const int F = 128;
    const int N = in_sizes[0] / F;
    const int E = in_sizes[1] / 2;
    const int ET = E + N;

    char* ws = (char*)d_ws;
    size_t off = 0;
    auto alloc = [&](size_t bytes) -> char* {
        char* p = ws + off;
        off += (bytes + 255) & ~(size_t)255;
        return p;
    };
    u16*   h     = (u16*)alloc((size_t)N * 512 * 2);
    u16*   h2    = (u16*)alloc((size_t)N * 512 * 2);
    u16*   xb    = (u16*)alloc((size_t)N * 128 * 2);
    u16*   w1t   = (u16*)alloc((size_t)512 * 128 * 2);
    u16*   w2t   = (u16*)alloc((size_t)64 * 512 * 2);
    int*   esrc  = (int*)alloc((size_t)ET * 4);
    float* als1  = (float*)alloc((size_t)N * 8 * 4);
    float* ald1  = (float*)alloc((size_t)N * 8 * 4);
    int*   deg   = (int*)alloc((size_t)N * 4);
    int*   offs  = (int*)alloc((size_t)(N + 1) * 4);
    int*   curs  = (int*)alloc((size_t)N * 4);

    // layer-2 buffers alias the h region (h is dead after agg1_fused)
    char* l2 = (char*)h;
    size_t o2 = 0;
    auto alloc2 = [&](size_t bytes) -> char* {
        char* p = l2 + o2;
        o2 += (bytes + 255) & ~(size_t)255;
        return p;
    };
    float* g    = (float*)alloc2((size_t)N * 40 * 4);
    float* als2 = (float*)alloc2((size_t)N * 4);
    float* ald2 = (float*)alloc2((size_t)N * 4);

    const int TPB = 256;
    const int* e_src = ei;
    const int* e_dst = ei + E;

    // prep + CSR build
    int prep_n = N * 32 + 512 * 128 + 64 * 512 + N;
    prep_kernel<<<(prep_n + TPB - 1) / TPB, TPB, 0, stream>>>(x, W1, W2, xb, w1t, w2t, deg, N);
    hist_kernel<<<(E + TPB - 1) / TPB, TPB, 0, stream>>>(e_dst, deg, E);
    scan_kernel<<<1, 1024, 0, stream>>>(deg, offs, curs, N);
    scatter_kernel<<<(ET + TPB - 1) / TPB, TPB, 0, stream>>>(e_src, e_dst, curs, esrc, E, N);

    // layer 1
    mfma_gemm<128, 128, true><<<dim3((N + 127) / 128, 4), 256, 0, stream>>>(
        xb, w1t, h, N, 128, 512, 512);
    logits1_kernel<<<(N * 8 + TPB - 1) / TPB, TPB, 0, stream>>>(h, a1s, a1d, als1, ald1, N);
    agg1_fused<<<N, 256, 0, stream>>>(offs, esrc, h, als1, ald1, b1, h2, N);

    // layer 2
    mfma_gemm<64, 64, false><<<dim3((N + 63) / 64, 1), 256, 0, stream>>>(
        h2, w2t, g, N, 512, 40, 40);
    logits2_kernel<<<(N + TPB - 1) / TPB, TPB, 0, stream>>>(g, a2s, a2d, als2, ald2, N);
    agg2_fused<<<(N + 1) / 2, 256, 0, stream>>>(offs, esrc, g, als2, ald2, b2, out, N);
}

// Round 5
// 527.999 us; speedup vs baseline: 1.4201x; 1.4201x over previous
//
#include <hip/hip_runtime.h>
#include <hip/hip_bf16.h>
#include <stdint.h>

typedef unsigned short u16;
typedef unsigned int u32;
typedef __attribute__((ext_vector_type(8))) __bf16 bf16x8;
typedef __attribute__((ext_vector_type(4))) float f32x4;

#define NEG_SLOPE 0.2f

__device__ __forceinline__ float bf2f(u16 u) {
    return __uint_as_float(((u32)u) << 16);
}
__device__ __forceinline__ u16 f2bf(float f) {
    u32 x = __float_as_uint(f);
    u32 r = (x + 0x7fffu + ((x >> 16) & 1u)) >> 16;  // round-to-nearest-even
    return (u16)r;
}
__device__ __forceinline__ float edge_w(float v) {
    v = v > 0.f ? v : NEG_SLOPE * v;  // LeakyReLU
    return __expf(v);
}

// ---------------- fused prep: cast x->bf16, transpose W1/W2, init deg ----------------

__global__ void prep_kernel(const float* __restrict__ x, const float* __restrict__ W1,
                            const float* __restrict__ W2, u16* __restrict__ xb,
                            u16* __restrict__ w1t, u16* __restrict__ w2t,
                            int* __restrict__ deg, int N) {
    int t = blockIdx.x * blockDim.x + threadIdx.x;
    int r1 = N * 32;            // x cast, float4 granules
    int r2 = r1 + 512 * 128;    // W1[128,512] -> w1t[512,128]
    int r3 = r2 + 64 * 512;     // W2[512,40] -> w2t[64,512] (pad rows 40..63)
    int r4 = r3 + N;            // deg init
    if (t < r1) {
        int base = t * 4;
        float4 v = *(const float4*)(x + base);
        xb[base + 0] = f2bf(v.x);
        xb[base + 1] = f2bf(v.y);
        xb[base + 2] = f2bf(v.z);
        xb[base + 3] = f2bf(v.w);
    } else if (t < r2) {
        int i = t - r1;
        int nn = i >> 7, k = i & 127;
        w1t[i] = f2bf(W1[k * 512 + nn]);
    } else if (t < r3) {
        int i = t - r2;
        int nn = i >> 9, k = i & 511;
        w2t[i] = (nn < 40) ? f2bf(W2[k * 40 + nn]) : (u16)0;
    } else if (t < r4) {
        deg[t - r3] = 1;  // self loop
    }
}

// ---------------- CSR build ----------------

__global__ void hist_kernel(const int* __restrict__ dst, int* deg, int E) {
    int e = blockIdx.x * blockDim.x + threadIdx.x;
    if (e < E) atomicAdd(&deg[dst[e]], 1);
}

__global__ void scan_kernel(const int* __restrict__ deg, int* offsets, int* cursor, int N) {
    __shared__ int s[1024];
    int t = threadIdx.x;
    int chunk = (N + 1023) / 1024;
    int beg = t * chunk;
    int end = beg + chunk; if (end > N) end = N; if (beg > N) beg = N;
    int sum = 0;
    for (int i = beg; i < end; i++) sum += deg[i];
    s[t] = sum;
    __syncthreads();
    for (int off = 1; off < 1024; off <<= 1) {
        int v = (t >= off) ? s[t - off] : 0;
        __syncthreads();
        s[t] += v;
        __syncthreads();
    }
    int run = s[t] - sum;  // exclusive prefix
    for (int i = beg; i < end; i++) {
        offsets[i] = run;
        cursor[i] = run;
        run += deg[i];
    }
    if (t == 1023) offsets[N] = s[1023];
}

__global__ void scatter_kernel(const int* __restrict__ src, const int* __restrict__ dst,
                               int* cursor, int* esrc, int E, int N) {
    int e = blockIdx.x * blockDim.x + threadIdx.x;
    if (e < E) {
        int d = dst[e];
        int idx = atomicAdd(&cursor[d], 1);
        esrc[idx] = src[e];
    } else if (e < E + N) {
        int i = e - E;
        int idx = atomicAdd(&cursor[i], 1);
        esrc[idx] = i;
    }
}

// ---------------- bf16 MFMA GEMM ----------------
// C[M, ldc] = A[M, K](bf16) @ Bt[Ncols, K](bf16)^T, store cols < Nstore.
// Block tile BM x BN, 4 waves in 2x2 of (BM/2)x(BN/2). LDS rows padded to
// 40 bf16 (80 B): 16-lane frag reads 2-way bank-aliased = free (m136).

template <int BM, int BN, bool CBF16>
__global__ __launch_bounds__(256) void mfma_gemm(
    const u16* __restrict__ A, const u16* __restrict__ Bt, void* __restrict__ Cv,
    int M, int K, int Nstore, int ldc) {
    constexpr int LDT = 40;
    constexpr int MI = BM / 32, NI = BN / 32;
    __shared__ u16 As[BM * LDT];
    __shared__ u16 Bs[BN * LDT];
    const int tid = threadIdx.x;
    const int r0 = blockIdx.x * BM;
    const int c0 = blockIdx.y * BN;
    const int lane = tid & 63, w = tid >> 6;
    const int quad = lane >> 4, l16 = lane & 15;
    const int wm = (w >> 1) * (BM / 2);
    const int wn = (w & 1) * (BN / 2);
    f32x4 acc[MI][NI] = {};

    for (int kc = 0; kc < K; kc += 32) {
        if constexpr (BM == 128) {
            int row = tid >> 1, half = tid & 1;
            int gr = r0 + row;
            uint4 v0 = make_uint4(0u, 0u, 0u, 0u), v1 = v0;
            if (gr < M) {
                const u16* p = A + (size_t)gr * K + kc + half * 16;
                v0 = *(const uint4*)p;
                v1 = *(const uint4*)(p + 8);
            }
            *(uint4*)&As[row * LDT + half * 16] = v0;
            *(uint4*)&As[row * LDT + half * 16 + 8] = v1;
        } else {  // BM == 64
            int row = tid >> 2, qo = (tid & 3) * 8;
            int gr = r0 + row;
            uint4 v = make_uint4(0u, 0u, 0u, 0u);
            if (gr < M) v = *(const uint4*)(A + (size_t)gr * K + kc + qo);
            *(uint4*)&As[row * LDT + qo] = v;
        }
        if constexpr (BN == 128) {
            int row = tid >> 1, half = tid & 1;
            const u16* p = Bt + (size_t)(c0 + row) * K + kc + half * 16;
            uint4 v0 = *(const uint4*)p;
            uint4 v1 = *(const uint4*)(p + 8);
            *(uint4*)&Bs[row * LDT + half * 16] = v0;
            *(uint4*)&Bs[row * LDT + half * 16 + 8] = v1;
        } else {  // BN == 64
            int row = tid >> 2, qo = (tid & 3) * 8;
            uint4 v = *(const uint4*)(Bt + (size_t)(c0 + row) * K + kc + qo);
            *(uint4*)&Bs[row * LDT + qo] = v;
        }
        __syncthreads();

        bf16x8 af[MI], bfr[NI];
#pragma unroll
        for (int mi = 0; mi < MI; mi++) {
            uint4 v = *(const uint4*)&As[(wm + mi * 16 + l16) * LDT + quad * 8];
            af[mi] = __builtin_bit_cast(bf16x8, v);
        }
#pragma unroll
        for (int ni = 0; ni < NI; ni++) {
            uint4 v = *(const uint4*)&Bs[(wn + ni * 16 + l16) * LDT + quad * 8];
            bfr[ni] = __builtin_bit_cast(bf16x8, v);
        }
#pragma unroll
        for (int mi = 0; mi < MI; mi++)
#pragma unroll
            for (int ni = 0; ni < NI; ni++)
                acc[mi][ni] = __builtin_amdgcn_mfma_f32_16x16x32_bf16(
                    af[mi], bfr[ni], acc[mi][ni], 0, 0, 0);
        __syncthreads();
    }
    // epilogue: D row = quad*4 + reg, col = l16 (verified m89/m91 mapping)
#pragma unroll
    for (int mi = 0; mi < MI; mi++) {
#pragma unroll
        for (int r = 0; r < 4; r++) {
            int gr = r0 + wm + mi * 16 + quad * 4 + r;
            if (gr >= M) continue;
#pragma unroll
            for (int ni = 0; ni < NI; ni++) {
                int gc = c0 + wn + ni * 16 + l16;
                if (gc >= Nstore) continue;
                if (CBF16)
                    ((u16*)Cv)[(size_t)gr * ldc + gc] = f2bf(acc[mi][ni][r]);
                else
                    ((float*)Cv)[(size_t)gr * ldc + gc] = acc[mi][ni][r];
            }
        }
    }
}

// ---------------- layer-1 attention ----------------

__global__ void logits1_kernel(const u16* __restrict__ h, const float* __restrict__ a_src,
                               const float* __restrict__ a_dst, float* als, float* ald, int N) {
    int t = blockIdx.x * blockDim.x + threadIdx.x;
    if (t >= N * 8) return;
    int n = t >> 3, hd = t & 7;
    const u16* row = h + (size_t)n * 512 + hd * 64;
    float s = 0.f, d = 0.f;
#pragma unroll
    for (int i = 0; i < 8; i++) {
        uint4 v = *(const uint4*)(row + i * 8);
        const u16* p = (const u16*)&v;
#pragma unroll
        for (int q = 0; q < 8; q++) {
            float x = bf2f(p[q]);
            s = fmaf(x, a_src[hd * 64 + i * 8 + q], s);
            d = fmaf(x, a_dst[hd * 64 + i * 8 + q], d);
        }
    }
    als[t] = s;
    ald[t] = d;
}

// Fused softmax + aggregation, layer 1. One WAVE per destination node
// (mean degree ~17 => no cross-wave split); 4-edge in-register unroll for
// memory-level parallelism; dual accumulators halve the FMA dep chain.
__global__ __launch_bounds__(256) void agg1_fused(
    const int* __restrict__ offs, const int* __restrict__ esrc,
    const u16* __restrict__ h, const float* __restrict__ als,
    const float* __restrict__ ald, const float* __restrict__ b1,
    u16* __restrict__ h2, int N) {
    int wid = blockIdx.x * 4 + (threadIdx.x >> 6);
    if (wid >= N) return;
    int lane = threadIdx.x & 63;
    int hd = lane >> 3;
    int b = offs[wid], e = offs[wid + 1];
    float ad = ald[wid * 8 + hd];
    float acc0[8] = {}, acc1[8] = {};
    float zs = 0.f;
    const u16* hp = h + (size_t)lane * 8;
    for (int jb = b; jb < e; jb += 64) {
        int nk = min(64, e - jb);
        int my = (jb + lane < e) ? esrc[jb + lane] : 0;
        int k = 0;
        for (; k + 4 <= nk; k += 4) {
            int s0 = __shfl(my, k);
            int s1 = __shfl(my, k + 1);
            int s2 = __shfl(my, k + 2);
            int s3 = __shfl(my, k + 3);
            // issue all 8 loads before any use
            uint4 h0 = *(const uint4*)(hp + (size_t)s0 * 512);
            uint4 h1 = *(const uint4*)(hp + (size_t)s1 * 512);
            uint4 h2v = *(const uint4*)(hp + (size_t)s2 * 512);
            uint4 h3 = *(const uint4*)(hp + (size_t)s3 * 512);
            float l0 = als[s0 * 8 + hd];
            float l1 = als[s1 * 8 + hd];
            float l2 = als[s2 * 8 + hd];
            float l3 = als[s3 * 8 + hd];
            float w0 = edge_w(l0 + ad), w1 = edge_w(l1 + ad);
            float w2 = edge_w(l2 + ad), w3 = edge_w(l3 + ad);
            zs += (w0 + w1) + (w2 + w3);
            const u16* p0 = (const u16*)&h0;
            const u16* p1 = (const u16*)&h1;
            const u16* p2 = (const u16*)&h2v;
            const u16* p3 = (const u16*)&h3;
#pragma unroll
            for (int q = 0; q < 8; q++) {
                acc0[q] = fmaf(w0, bf2f(p0[q]), fmaf(w2, bf2f(p2[q]), acc0[q]));
                acc1[q] = fmaf(w1, bf2f(p1[q]), fmaf(w3, bf2f(p3[q]), acc1[q]));
            }
        }
        for (; k < nk; k++) {
            int s = __shfl(my, k);
            uint4 hv = *(const uint4*)(hp + (size_t)s * 512);
            float w = edge_w(als[s * 8 + hd] + ad);
            zs += w;
            const u16* p = (const u16*)&hv;
#pragma unroll
            for (int q = 0; q < 8; q++) acc0[q] = fmaf(w, bf2f(p[q]), acc0[q]);
        }
    }
    float zi = 1.f / zs;  // >0: self loop guarantees an edge
#pragma unroll
    for (int q = 0; q < 8; q++) {
        float val = fmaf(acc0[q] + acc1[q], zi, b1[lane * 8 + q]);
        val = val > 0.f ? val : 0.f;  // inter-layer ReLU
        h2[(size_t)wid * 512 + lane * 8 + q] = f2bf(val);
    }
}

// ---------------- layer-2 attention ----------------

__global__ void logits2_kernel(const float* __restrict__ g, const float* __restrict__ a_src,
                               const float* __restrict__ a_dst, float* als, float* ald, int N) {
    int n = blockIdx.x * blockDim.x + threadIdx.x;
    if (n >= N) return;
    const float* row = g + (size_t)n * 40;
    float s = 0.f, d = 0.f;
#pragma unroll
    for (int i = 0; i < 10; i++) {
        float4 v = *(const float4*)(row + i * 4);
        float vv[4] = {v.x, v.y, v.z, v.w};
#pragma unroll
        for (int q = 0; q < 4; q++) {
            s = fmaf(vv[q], a_src[i * 4 + q], s);
            d = fmaf(vv[q], a_dst[i * 4 + q], d);
        }
    }
    als[n] = s;
    ald[n] = d;
}

// Fused softmax + aggregation, layer 2. One wave per node, 4-edge unroll.
__global__ __launch_bounds__(256) void agg2_fused(
    const int* __restrict__ offs, const int* __restrict__ esrc,
    const float* __restrict__ g, const float* __restrict__ als,
    const float* __restrict__ ald, const float* __restrict__ b2,
    float* __restrict__ out, int N) {
    int wid = blockIdx.x * 4 + (threadIdx.x >> 6);
    if (wid >= N) return;
    int lane = threadIdx.x & 63;
    int b = offs[wid], e = offs[wid + 1];
    float ad = ald[wid];
    float acc0 = 0.f, acc1 = 0.f, zs = 0.f;
    bool active = lane < 40;
    for (int jb = b; jb < e; jb += 64) {
        int nk = min(64, e - jb);
        int my = (jb + lane < e) ? esrc[jb + lane] : 0;
        int k = 0;
        for (; k + 4 <= nk; k += 4) {
            int s0 = __shfl(my, k);
            int s1 = __shfl(my, k + 1);
            int s2 = __shfl(my, k + 2);
            int s3 = __shfl(my, k + 3);
            float g0 = active ? g[(size_t)s0 * 40 + lane] : 0.f;
            float g1 = active ? g[(size_t)s1 * 40 + lane] : 0.f;
            float g2 = active ? g[(size_t)s2 * 40 + lane] : 0.f;
            float g3 = active ? g[(size_t)s3 * 40 + lane] : 0.f;
            float l0 = als[s0], l1 = als[s1], l2 = als[s2], l3 = als[s3];
            float w0 = edge_w(l0 + ad), w1 = edge_w(l1 + ad);
            float w2 = edge_w(l2 + ad), w3 = edge_w(l3 + ad);
            zs += (w0 + w1) + (w2 + w3);
            acc0 = fmaf(w0, g0, fmaf(w2, g2, acc0));
            acc1 = fmaf(w1, g1, fmaf(w3, g3, acc1));
        }
        for (; k < nk; k++) {
            int s = __shfl(my, k);
            float gv = active ? g[(size_t)s * 40 + lane] : 0.f;
            float w = edge_w(als[s] + ad);
            zs += w;
            acc0 = fmaf(w, gv, acc0);
        }
    }
    if (active) out[(size_t)wid * 40 + lane] = (acc0 + acc1) / zs + b2[lane];
}

// ---------------- host launch ----------------

extern "C" void kernel_launch(void* const* d_in, const int* in_sizes, int n_in,
                              void* d_out, int out_size, void* d_ws, size_t ws_size,
                              hipStream_t stream) {
    const float* x   = (const float*)d_in[0];
    const int*   ei  = (const int*)d_in[1];
    const float* W1  = (const float*)d_in[2];
    const float* a1s = (const float*)d_in[3];
    const float* a1d = (const float*)d_in[4];
    const float* b1  = (const float*)d_in[5];
    const float* W2  = (const float*)d_in[6];
    const float* a2s = (const float*)d_in[7];
    const float* a2d = (const float*)d_in[8];
    const float* b2  = (const float*)d_in[9];
    float* out = (float*)d_out;

    const int F = 128;
    const int N = in_sizes[0] / F;
    const int E = in_sizes[1] / 2;
    const int ET = E + N;

    char* ws = (char*)d_ws;
    size_t off = 0;
    auto alloc = [&](size_t bytes) -> char* {
        char* p = ws + off;
        off += (bytes + 255) & ~(size_t)255;
        return p;
    };
    u16*   h     = (u16*)alloc((size_t)N * 512 * 2);
    u16*   h2    = (u16*)alloc((size_t)N * 512 * 2);
    u16*   xb    = (u16*)alloc((size_t)N * 128 * 2);
    u16*   w1t   = (u16*)alloc((size_t)512 * 128 * 2);
    u16*   w2t   = (u16*)alloc((size_t)64 * 512 * 2);
    int*   esrc  = (int*)alloc((size_t)ET * 4);
    float* als1  = (float*)alloc((size_t)N * 8 * 4);
    float* ald1  = (float*)alloc((size_t)N * 8 * 4);
    int*   deg   = (int*)alloc((size_t)N * 4);
    int*   offs  = (int*)alloc((size_t)(N + 1) * 4);
    int*   curs  = (int*)alloc((size_t)N * 4);

    // layer-2 buffers alias the h region (h is dead after agg1_fused)
    char* l2 = (char*)h;
    size_t o2 = 0;
    auto alloc2 = [&](size_t bytes) -> char* {
        char* p = l2 + o2;
        o2 += (bytes + 255) & ~(size_t)255;
        return p;
    };
    float* g    = (float*)alloc2((size_t)N * 40 * 4);
    float* als2 = (float*)alloc2((size_t)N * 4);
    float* ald2 = (float*)alloc2((size_t)N * 4);

    const int TPB = 256;
    const int* e_src = ei;
    const int* e_dst = ei + E;

    // prep + CSR build
    int prep_n = N * 32 + 512 * 128 + 64 * 512 + N;
    prep_kernel<<<(prep_n + TPB - 1) / TPB, TPB, 0, stream>>>(x, W1, W2, xb, w1t, w2t, deg, N);
    hist_kernel<<<(E + TPB - 1) / TPB, TPB, 0, stream>>>(e_dst, deg, E);
    scan_kernel<<<1, 1024, 0, stream>>>(deg, offs, curs, N);
    scatter_kernel<<<(ET + TPB - 1) / TPB, TPB, 0, stream>>>(e_src, e_dst, curs, esrc, E, N);

    // layer 1
    mfma_gemm<128, 128, true><<<dim3((N + 127) / 128, 4), 256, 0, stream>>>(
        xb, w1t, h, N, 128, 512, 512);
    logits1_kernel<<<(N * 8 + TPB - 1) / TPB, TPB, 0, stream>>>(h, a1s, a1d, als1, ald1, N);
    agg1_fused<<<(N + 3) / 4, 256, 0, stream>>>(offs, esrc, h, als1, ald1, b1, h2, N);

    // layer 2
    mfma_gemm<64, 64, false><<<dim3((N + 63) / 64, 1), 256, 0, stream>>>(
        h2, w2t, g, N, 512, 40, 40);
    logits2_kernel<<<(N + TPB - 1) / TPB, TPB, 0, stream>>>(g, a2s, a2d, als2, ald2, N);
    agg2_fused<<<(N + 3) / 4, 256, 0, stream>>>(offs, esrc, g, als2, ald2, b2, out, N);
}

// Round 7
// 501.567 us; speedup vs baseline: 1.4949x; 1.0527x over previous
//
#include <hip/hip_runtime.h>
#include <hip/hip_bf16.h>
#include <stdint.h>

typedef unsigned short u16;
typedef unsigned int u32;
typedef __attribute__((ext_vector_type(8))) __bf16 bf16x8;
typedef __attribute__((ext_vector_type(4))) float f32x4;
typedef __attribute__((ext_vector_type(4))) unsigned int u32x4;

#define NEG_SLOPE 0.2f

__device__ __forceinline__ float bf2f(u16 u) {
    return __uint_as_float(((u32)u) << 16);
}
__device__ __forceinline__ u16 f2bf(float f) {
    u32 x = __float_as_uint(f);
    u32 r = (x + 0x7fffu + ((x >> 16) & 1u)) >> 16;  // round-to-nearest-even
    return (u16)r;
}
__device__ __forceinline__ float edge_w(float v) {
    v = v > 0.f ? v : NEG_SLOPE * v;  // LeakyReLU
    return __expf(v);
}

// ---------------- CSR + prep ----------------

__global__ void init_deg_kernel(int* deg, int N) {
    int i = blockIdx.x * blockDim.x + threadIdx.x;
    if (i < N) deg[i] = 0;  // self-loop handled by +1 in scan
}

// hist + cast x->bf16 + transpose W1/W2, one kernel (independent ranges)
__global__ void setup_kernel(const int* __restrict__ dst, int* __restrict__ deg,
                             const float* __restrict__ x, const float* __restrict__ W1,
                             const float* __restrict__ W2, u16* __restrict__ xb,
                             u16* __restrict__ w1t, u16* __restrict__ w2t,
                             int E, int N) {
    int t = blockIdx.x * blockDim.x + threadIdx.x;
    int rE = E;
    int r1 = rE + N * 32;          // x cast, float4 granules
    int r2 = r1 + 512 * 128;       // W1[128,512] -> w1t[512,128]
    int r3 = r2 + 64 * 512;        // W2[512,40] -> w2t[64,512] (rows 40..63 zero)
    if (t < rE) {
        atomicAdd(&deg[dst[t]], 1);
    } else if (t < r1) {
        int base = (t - rE) * 4;
        float4 v = *(const float4*)(x + base);
        xb[base + 0] = f2bf(v.x);
        xb[base + 1] = f2bf(v.y);
        xb[base + 2] = f2bf(v.z);
        xb[base + 3] = f2bf(v.w);
    } else if (t < r2) {
        int i = t - r1;
        int nn = i >> 7, k = i & 127;
        w1t[i] = f2bf(W1[k * 512 + nn]);
    } else if (t < r3) {
        int i = t - r2;
        int nn = i >> 9, k = i & 511;
        w2t[i] = (nn < 40) ? f2bf(W2[k * 40 + nn]) : (u16)0;
    }
}

__global__ void scan_kernel(const int* __restrict__ deg, int* offsets, int* cursor, int N) {
    __shared__ int s[1024];
    int t = threadIdx.x;
    int chunk = (N + 1023) / 1024;
    int beg = t * chunk;
    int end = beg + chunk; if (end > N) end = N; if (beg > N) beg = N;
    int sum = 0;
    for (int i = beg; i < end; i++) sum += deg[i] + 1;  // +1 self loop
    s[t] = sum;
    __syncthreads();
    for (int off = 1; off < 1024; off <<= 1) {
        int v = (t >= off) ? s[t - off] : 0;
        __syncthreads();
        s[t] += v;
        __syncthreads();
    }
    int run = s[t] - sum;  // exclusive prefix
    for (int i = beg; i < end; i++) {
        offsets[i] = run;
        cursor[i] = run;
        run += deg[i] + 1;
    }
    if (t == 1023) offsets[N] = s[1023];
}

__global__ void scatter_kernel(const int* __restrict__ src, const int* __restrict__ dst,
                               int* cursor, int* esrc, int E, int N) {
    int e = blockIdx.x * blockDim.x + threadIdx.x;
    if (e < E) {
        int d = dst[e];
        int idx = atomicAdd(&cursor[d], 1);
        esrc[idx] = src[e];
    } else if (e < E + N) {
        int i = e - E;
        int idx = atomicAdd(&cursor[i], 1);
        esrc[idx] = i;
    }
}

// ---------------- GEMM1 (x @ W1 -> h bf16) + fused logits1 ----------------
// A = xb[N,128] bf16, Bt = w1t[512,128] bf16. Block tile 128x128, 4 waves
// 2x2 of 64x64. BK=64, 2 k-phases. LDS rows padded 64+8 (2-way bank alias,
// free). Epilogue computes als1/ald1 = h . a1{s,d} per head via 16-lane
// shfl reduction (each wave's col-quadrant = exactly one head).

__global__ __launch_bounds__(256) void gemm1_fused(
    const u16* __restrict__ A, const u16* __restrict__ Bt,
    const float* __restrict__ a1s, const float* __restrict__ a1d,
    u16* __restrict__ h, float* __restrict__ als, float* __restrict__ ald, int M) {
    constexpr int LDT = 72;  // 64 + 8 pad
    __shared__ u16 As[128 * LDT];
    __shared__ u16 Bs[128 * LDT];
    const int tid = threadIdx.x;
    const int r0 = blockIdx.x * 128;
    const int c0 = blockIdx.y * 128;
    const int lane = tid & 63, w = tid >> 6;
    const int quad = lane >> 4, l16 = lane & 15;
    const int wm = (w >> 1) * 64;
    const int wn = (w & 1) * 64;
    const int head = (c0 + wn) >> 6;
    f32x4 acc[4][4] = {};

    // attention vector constants for this wave's 64-col head slice
    float asc[4], adc[4];
#pragma unroll
    for (int ni = 0; ni < 4; ni++) {
        asc[ni] = a1s[head * 64 + ni * 16 + l16];
        adc[ni] = a1d[head * 64 + ni * 16 + l16];
    }

    for (int kc = 0; kc < 128; kc += 64) {
        {
            int row = tid >> 1, half = tid & 1;
            int gr = r0 + row;
            uint4 v0 = make_uint4(0u, 0u, 0u, 0u), v1 = v0, v2 = v0, v3 = v0;
            if (gr < M) {
                const u16* p = A + (size_t)gr * 128 + kc + half * 32;
                v0 = *(const uint4*)p;
                v1 = *(const uint4*)(p + 8);
                v2 = *(const uint4*)(p + 16);
                v3 = *(const uint4*)(p + 24);
            }
            u16* d = &As[row * LDT + half * 32];
            *(uint4*)(d + 0) = v0;
            *(uint4*)(d + 8) = v1;
            *(uint4*)(d + 16) = v2;
            *(uint4*)(d + 24) = v3;
        }
        {
            int row = tid >> 1, half = tid & 1;
            const u16* p = Bt + (size_t)(c0 + row) * 128 + kc + half * 32;
            uint4 v0 = *(const uint4*)p;
            uint4 v1 = *(const uint4*)(p + 8);
            uint4 v2 = *(const uint4*)(p + 16);
            uint4 v3 = *(const uint4*)(p + 24);
            u16* d = &Bs[row * LDT + half * 32];
            *(uint4*)(d + 0) = v0;
            *(uint4*)(d + 8) = v1;
            *(uint4*)(d + 16) = v2;
            *(uint4*)(d + 24) = v3;
        }
        __syncthreads();
#pragma unroll
        for (int kst = 0; kst < 2; kst++) {
            bf16x8 af[4], bfr[4];
#pragma unroll
            for (int mi = 0; mi < 4; mi++) {
                uint4 v = *(const uint4*)&As[(wm + mi * 16 + l16) * LDT + kst * 32 + quad * 8];
                af[mi] = __builtin_bit_cast(bf16x8, v);
            }
#pragma unroll
            for (int ni = 0; ni < 4; ni++) {
                uint4 v = *(const uint4*)&Bs[(wn + ni * 16 + l16) * LDT + kst * 32 + quad * 8];
                bfr[ni] = __builtin_bit_cast(bf16x8, v);
            }
#pragma unroll
            for (int mi = 0; mi < 4; mi++)
#pragma unroll
                for (int ni = 0; ni < 4; ni++)
                    acc[mi][ni] = __builtin_amdgcn_mfma_f32_16x16x32_bf16(
                        af[mi], bfr[ni], acc[mi][ni], 0, 0, 0);
        }
        __syncthreads();
    }
    // epilogue: store h + fused attention dots
#pragma unroll
    for (int mi = 0; mi < 4; mi++) {
#pragma unroll
        for (int r = 0; r < 4; r++) {
            int gr = r0 + wm + mi * 16 + quad * 4 + r;
            float ps = 0.f, pd = 0.f;
#pragma unroll
            for (int ni = 0; ni < 4; ni++) {
                float v = acc[mi][ni][r];
                ps = fmaf(v, asc[ni], ps);
                pd = fmaf(v, adc[ni], pd);
                if (gr < M) {
                    int gc = c0 + wn + ni * 16 + l16;
                    h[(size_t)gr * 512 + gc] = f2bf(v);
                }
            }
            // reduce over the 16 l16 lanes (xor masks stay in-group)
#pragma unroll
            for (int m = 8; m >= 1; m >>= 1) {
                ps += __shfl_xor(ps, m);
                pd += __shfl_xor(pd, m);
            }
            if (l16 == 0 && gr < M) {
                als[gr * 8 + head] = ps;
                ald[gr * 8 + head] = pd;
            }
        }
    }
}

// ---------------- GEMM2 (h2 @ W2 -> g fp32) + fused logits2 ----------------
// A = h2[N,512] bf16, Bt = w2t[64,512] bf16 (cols 40..63 zero). Block 64
// rows, 4 waves x 16 rows, each wave covers all 64 cols. BK=128, 4 phases.

__global__ __launch_bounds__(256) void gemm2_fused(
    const u16* __restrict__ A, const u16* __restrict__ Bt,
    const float* __restrict__ a2s, const float* __restrict__ a2d,
    float* __restrict__ g, float* __restrict__ als, float* __restrict__ ald, int M) {
    constexpr int LDT = 136;  // 128 + 8 pad
    __shared__ u16 As[64 * LDT];
    __shared__ u16 Bs[64 * LDT];
    const int tid = threadIdx.x;
    const int r0 = blockIdx.x * 64;
    const int lane = tid & 63, w = tid >> 6;
    const int quad = lane >> 4, l16 = lane & 15;
    f32x4 acc[4] = {};

    float asc[4], adc[4];
#pragma unroll
    for (int ni = 0; ni < 4; ni++) {
        int gc = ni * 16 + l16;
        asc[ni] = (gc < 40) ? a2s[gc] : 0.f;
        adc[ni] = (gc < 40) ? a2d[gc] : 0.f;
    }

    for (int kc = 0; kc < 512; kc += 128) {
        {
            int row = tid >> 2, q = tid & 3;
            int gr = r0 + row;
            uint4 v0 = make_uint4(0u, 0u, 0u, 0u), v1 = v0, v2 = v0, v3 = v0;
            if (gr < M) {
                const u16* p = A + (size_t)gr * 512 + kc + q * 32;
                v0 = *(const uint4*)p;
                v1 = *(const uint4*)(p + 8);
                v2 = *(const uint4*)(p + 16);
                v3 = *(const uint4*)(p + 24);
            }
            u16* d = &As[row * LDT + q * 32];
            *(uint4*)(d + 0) = v0;
            *(uint4*)(d + 8) = v1;
            *(uint4*)(d + 16) = v2;
            *(uint4*)(d + 24) = v3;
        }
        {
            int row = tid >> 2, q = tid & 3;
            const u16* p = Bt + (size_t)row * 512 + kc + q * 32;
            uint4 v0 = *(const uint4*)p;
            uint4 v1 = *(const uint4*)(p + 8);
            uint4 v2 = *(const uint4*)(p + 16);
            uint4 v3 = *(const uint4*)(p + 24);
            u16* d = &Bs[row * LDT + q * 32];
            *(uint4*)(d + 0) = v0;
            *(uint4*)(d + 8) = v1;
            *(uint4*)(d + 16) = v2;
            *(uint4*)(d + 24) = v3;
        }
        __syncthreads();
#pragma unroll
        for (int kst = 0; kst < 4; kst++) {
            uint4 va = *(const uint4*)&As[(w * 16 + l16) * LDT + kst * 32 + quad * 8];
            bf16x8 af = __builtin_bit_cast(bf16x8, va);
#pragma unroll
            for (int ni = 0; ni < 4; ni++) {
                uint4 vb = *(const uint4*)&Bs[(ni * 16 + l16) * LDT + kst * 32 + quad * 8];
                bf16x8 bf = __builtin_bit_cast(bf16x8, vb);
                acc[ni] = __builtin_amdgcn_mfma_f32_16x16x32_bf16(af, bf, acc[ni], 0, 0, 0);
            }
        }
        __syncthreads();
    }
#pragma unroll
    for (int r = 0; r < 4; r++) {
        int gr = r0 + w * 16 + quad * 4 + r;
        float ps = 0.f, pd = 0.f;
#pragma unroll
        for (int ni = 0; ni < 4; ni++) {
            float v = acc[ni][r];
            ps = fmaf(v, asc[ni], ps);
            pd = fmaf(v, adc[ni], pd);
            int gc = ni * 16 + l16;
            if (gr < M && gc < 40) g[(size_t)gr * 40 + gc] = v;
        }
#pragma unroll
        for (int m = 8; m >= 1; m >>= 1) {
            ps += __shfl_xor(ps, m);
            pd += __shfl_xor(pd, m);
        }
        if (l16 == 0 && gr < M) {
            als[gr] = ps;
            ald[gr] = pd;
        }
    }
}

// ---------------- fused softmax+aggregation, layer 1 ----------------
// One wave per destination node; 4-edge in-register unroll; nontemporal
// h2 store (one 16B/lane) to keep h read-resident in L2.
__global__ __launch_bounds__(256) void agg1_fused(
    const int* __restrict__ offs, const int* __restrict__ esrc,
    const u16* __restrict__ h, const float* __restrict__ als,
    const float* __restrict__ ald, const float* __restrict__ b1,
    u16* __restrict__ h2, int N) {
    int wid = blockIdx.x * 4 + (threadIdx.x >> 6);
    if (wid >= N) return;
    int lane = threadIdx.x & 63;
    int hd = lane >> 3;
    int b = offs[wid], e = offs[wid + 1];
    float ad = ald[wid * 8 + hd];
    float acc0[8] = {}, acc1[8] = {};
    float zs = 0.f;
    const u16* hp = h + (size_t)lane * 8;
    for (int jb = b; jb < e; jb += 64) {
        int nk = min(64, e - jb);
        int my = (jb + lane < e) ? esrc[jb + lane] : 0;
        int k = 0;
        for (; k + 4 <= nk; k += 4) {
            int s0 = __shfl(my, k);
            int s1 = __shfl(my, k + 1);
            int s2 = __shfl(my, k + 2);
            int s3 = __shfl(my, k + 3);
            uint4 h0 = *(const uint4*)(hp + (size_t)s0 * 512);
            uint4 h1 = *(const uint4*)(hp + (size_t)s1 * 512);
            uint4 h2v = *(const uint4*)(hp + (size_t)s2 * 512);
            uint4 h3 = *(const uint4*)(hp + (size_t)s3 * 512);
            float l0 = als[s0 * 8 + hd];
            float l1 = als[s1 * 8 + hd];
            float l2 = als[s2 * 8 + hd];
            float l3 = als[s3 * 8 + hd];
            float w0 = edge_w(l0 + ad), w1 = edge_w(l1 + ad);
            float w2 = edge_w(l2 + ad), w3 = edge_w(l3 + ad);
            zs += (w0 + w1) + (w2 + w3);
            const u16* p0 = (const u16*)&h0;
            const u16* p1 = (const u16*)&h1;
            const u16* p2 = (const u16*)&h2v;
            const u16* p3 = (const u16*)&h3;
#pragma unroll
            for (int q = 0; q < 8; q++) {
                acc0[q] = fmaf(w0, bf2f(p0[q]), fmaf(w2, bf2f(p2[q]), acc0[q]));
                acc1[q] = fmaf(w1, bf2f(p1[q]), fmaf(w3, bf2f(p3[q]), acc1[q]));
            }
        }
        for (; k < nk; k++) {
            int s = __shfl(my, k);
            uint4 hv = *(const uint4*)(hp + (size_t)s * 512);
            float w = edge_w(als[s * 8 + hd] + ad);
            zs += w;
            const u16* p = (const u16*)&hv;
#pragma unroll
            for (int q = 0; q < 8; q++) acc0[q] = fmaf(w, bf2f(p[q]), acc0[q]);
        }
    }
    float zi = 1.f / zs;  // >0: self loop guarantees an edge
    u16 packed[8];
#pragma unroll
    for (int q = 0; q < 8; q++) {
        float val = fmaf(acc0[q] + acc1[q], zi, b1[lane * 8 + q]);
        val = val > 0.f ? val : 0.f;  // inter-layer ReLU
        packed[q] = f2bf(val);
    }
    u32x4 pv;
    pv.x = (u32)packed[0] | ((u32)packed[1] << 16);
    pv.y = (u32)packed[2] | ((u32)packed[3] << 16);
    pv.z = (u32)packed[4] | ((u32)packed[5] << 16);
    pv.w = (u32)packed[6] | ((u32)packed[7] << 16);
    __builtin_nontemporal_store(pv, (u32x4*)&h2[(size_t)wid * 512 + lane * 8]);
}

// ---------------- fused softmax+aggregation, layer 2 ----------------
// One wave per node, 8-edge unroll, 4 accumulators; lane = class (<40).
__global__ __launch_bounds__(256) void agg2_fused(
    const int* __restrict__ offs, const int* __restrict__ esrc,
    const float* __restrict__ g, const float* __restrict__ als,
    const float* __restrict__ ald, const float* __restrict__ b2,
    float* __restrict__ out, int N) {
    int wid = blockIdx.x * 4 + (threadIdx.x >> 6);
    if (wid >= N) return;
    int lane = threadIdx.x & 63;
    int b = offs[wid], e = offs[wid + 1];
    float ad = ald[wid];
    float acc0 = 0.f, acc1 = 0.f, acc2 = 0.f, acc3 = 0.f, zs = 0.f;
    bool active = lane < 40;
    for (int jb = b; jb < e; jb += 64) {
        int nk = min(64, e - jb);
        int my = (jb + lane < e) ? esrc[jb + lane] : 0;
        int k = 0;
        for (; k + 8 <= nk; k += 8) {
            int s0 = __shfl(my, k + 0), s1 = __shfl(my, k + 1);
            int s2 = __shfl(my, k + 2), s3 = __shfl(my, k + 3);
            int s4 = __shfl(my, k + 4), s5 = __shfl(my, k + 5);
            int s6 = __shfl(my, k + 6), s7 = __shfl(my, k + 7);
            float g0 = active ? g[(size_t)s0 * 40 + lane] : 0.f;
            float g1 = active ? g[(size_t)s1 * 40 + lane] : 0.f;
            float g2 = active ? g[(size_t)s2 * 40 + lane] : 0.f;
            float g3 = active ? g[(size_t)s3 * 40 + lane] : 0.f;
            float g4 = active ? g[(size_t)s4 * 40 + lane] : 0.f;
            float g5 = active ? g[(size_t)s5 * 40 + lane] : 0.f;
            float g6 = active ? g[(size_t)s6 * 40 + lane] : 0.f;
            float g7 = active ? g[(size_t)s7 * 40 + lane] : 0.f;
            float w0 = edge_w(als[s0] + ad), w1 = edge_w(als[s1] + ad);
            float w2 = edge_w(als[s2] + ad), w3 = edge_w(als[s3] + ad);
            float w4 = edge_w(als[s4] + ad), w5 = edge_w(als[s5] + ad);
            float w6 = edge_w(als[s6] + ad), w7 = edge_w(als[s7] + ad);
            zs += ((w0 + w1) + (w2 + w3)) + ((w4 + w5) + (w6 + w7));
            acc0 = fmaf(w0, g0, acc0);
            acc1 = fmaf(w1, g1, acc1);
            acc2 = fmaf(w2, g2, acc2);
            acc3 = fmaf(w3, g3, acc3);
            acc0 = fmaf(w4, g4, acc0);
            acc1 = fmaf(w5, g5, acc1);
            acc2 = fmaf(w6, g6, acc2);
            acc3 = fmaf(w7, g7, acc3);
        }
        for (; k < nk; k++) {
            int s = __shfl(my, k);
            float gv = active ? g[(size_t)s * 40 + lane] : 0.f;
            float w = edge_w(als[s] + ad);
            zs += w;
            acc0 = fmaf(w, gv, acc0);
        }
    }
    if (active)
        out[(size_t)wid * 40 + lane] = ((acc0 + acc1) + (acc2 + acc3)) / zs + b2[lane];
}

// ---------------- host launch ----------------

extern "C" void kernel_launch(void* const* d_in, const int* in_sizes, int n_in,
                              void* d_out, int out_size, void* d_ws, size_t ws_size,
                              hipStream_t stream) {
    const float* x   = (const float*)d_in[0];
    const int*   ei  = (const int*)d_in[1];
    const float* W1  = (const float*)d_in[2];
    const float* a1s = (const float*)d_in[3];
    const float* a1d = (const float*)d_in[4];
    const float* b1  = (const float*)d_in[5];
    const float* W2  = (const float*)d_in[6];
    const float* a2s = (const float*)d_in[7];
    const float* a2d = (const float*)d_in[8];
    const float* b2  = (const float*)d_in[9];
    float* out = (float*)d_out;

    const int F = 128;
    const int N = in_sizes[0] / F;
    const int E = in_sizes[1] / 2;
    const int ET = E + N;

    char* ws = (char*)d_ws;
    size_t off = 0;
    auto alloc = [&](size_t bytes) -> char* {
        char* p = ws + off;
        off += (bytes + 255) & ~(size_t)255;
        return p;
    };
    u16*   h     = (u16*)alloc((size_t)N * 512 * 2);
    u16*   h2    = (u16*)alloc((size_t)N * 512 * 2);
    u16*   xb    = (u16*)alloc((size_t)N * 128 * 2);
    u16*   w1t   = (u16*)alloc((size_t)512 * 128 * 2);
    u16*   w2t   = (u16*)alloc((size_t)64 * 512 * 2);
    int*   esrc  = (int*)alloc((size_t)ET * 4);
    float* als1  = (float*)alloc((size_t)N * 8 * 4);
    float* ald1  = (float*)alloc((size_t)N * 8 * 4);
    int*   deg   = (int*)alloc((size_t)N * 4);
    int*   offs  = (int*)alloc((size_t)(N + 1) * 4);
    int*   curs  = (int*)alloc((size_t)N * 4);

    // layer-2 buffers alias the h region (h is dead after agg1_fused)
    char* l2 = (char*)h;
    size_t o2 = 0;
    auto alloc2 = [&](size_t bytes) -> char* {
        char* p = l2 + o2;
        o2 += (bytes + 255) & ~(size_t)255;
        return p;
    };
    float* g    = (float*)alloc2((size_t)N * 40 * 4);
    float* als2 = (float*)alloc2((size_t)N * 4);
    float* ald2 = (float*)alloc2((size_t)N * 4);

    const int TPB = 256;
    const int* e_src = ei;
    const int* e_dst = ei + E;

    // CSR + prep
    init_deg_kernel<<<(N + TPB - 1) / TPB, TPB, 0, stream>>>(deg, N);
    int setup_n = E + N * 32 + 512 * 128 + 64 * 512;
    setup_kernel<<<(setup_n + TPB - 1) / TPB, TPB, 0, stream>>>(
        e_dst, deg, x, W1, W2, xb, w1t, w2t, E, N);
    scan_kernel<<<1, 1024, 0, stream>>>(deg, offs, curs, N);
    scatter_kernel<<<(ET + TPB - 1) / TPB, TPB, 0, stream>>>(e_src, e_dst, curs, esrc, E, N);

    // layer 1
    gemm1_fused<<<dim3((N + 127) / 128, 4), 256, 0, stream>>>(
        xb, w1t, a1s, a1d, h, als1, ald1, N);
    agg1_fused<<<(N + 3) / 4, 256, 0, stream>>>(offs, esrc, h, als1, ald1, b1, h2, N);

    // layer 2
    gemm2_fused<<<(N + 63) / 64, 256, 0, stream>>>(h2, w2t, a2s, a2d, g, als2, ald2, N);
    agg2_fused<<<(N + 3) / 4, 256, 0, stream>>>(offs, esrc, g, als2, ald2, b2, out, N);
}